// Round 2
// baseline (845.975 us; speedup 1.0000x reference)
//
#include <hip/hip_runtime.h>
#include <hip/hip_bf16.h>

// Qriaffine: out[n,i,j] = sum_{a,b,c,d} l1[n,i,a] W[a,b,c,d] l2[n,j,b] h1[n,i,c] h2[n,j,d]
// Plan:
//   P[(n,i)][(a*65+c)] = l1[a]*h1[c]        (8192 x 4225, bf16, pad K->4288)
//   Wt2[(b*65+d)][(a*65+c)] = W[a,b,c,d]    (4225 x 4225, bf16, pad -> 4352 x 4288)
//   Q = P @ Wt2 (NT gemm)                   (8192 x 4352, bf16)
//   R[(n,j)][(b*65+d)] = l2[b]*h2[d]        (8192 x 4352, bf16, built AFTER gemm1)
//   out_n = Q_n @ R_n^T (NT gemm, f32 out)  (8 x 1024 x 1024)
//
// R4 (resubmit after GPU-acquisition timeout; no counters came back):
// gemm1 moved to a deep-pipelined 256x256 kernel (T3+T4+T5):
//   BK=32, 512 thr / 8 waves (2Mx4N, 128x64 per wave), 4-deep LDS ring
//   (128 KiB), prefetch distance 2 K-tiles, ONE barrier per K-tile with
//   counted s_waitcnt vmcnt(4) (never 0 in steady state), setprio around
//   the 16-MFMA cluster, chunk swizzle p = c^(row&3) (pre-swizzled global
//   src + linear DMA dest) -> conflict-free ds_read_b128 & DMA writes.
// gemm2 keeps the R3 128x128 kernel (512 blocks; 256^2 would leave half
// the CUs idle at grid=128).

typedef __attribute__((ext_vector_type(8))) short short8;     // 8 bf16 = 4 VGPRs
typedef __attribute__((ext_vector_type(16))) float floatx16;  // MFMA 32x32 acc

#define KP 4288   // padded (a,c) dim: 67*64
#define DP 4352   // padded (b,d) dim: 68*64 = 17*256
#define NROW 8192 // n*L

__device__ __forceinline__ void async_ld16(const void* g, void* l) {
  __builtin_amdgcn_global_load_lds(
      (const __attribute__((address_space(1))) unsigned int*)g,
      (__attribute__((address_space(3))) unsigned int*)l, 16, 0, 0);
}

// ---------------- zero helper (16B granularity) ----------------
__global__ void zero_kernel(float4* __restrict__ p, long n) {
  long i = (long)blockIdx.x * blockDim.x + threadIdx.x;
  long stride = (long)gridDim.x * blockDim.x;
  float4 z = make_float4(0.f, 0.f, 0.f, 0.f);
  for (; i < n; i += stride) p[i] = z;
}

// ---------------- W[a,b,c,d] -> Wt2[(b*65+d)][(a*65+c)] (bf16) ----------------
__global__ void build_wt2(const float* __restrict__ W, __hip_bfloat16* __restrict__ Wt2) {
  __shared__ __hip_bfloat16 tile[65 * 66];
  const int a = blockIdx.x, b = blockIdx.y;
  const float* src = W + (size_t)(a * 65 + b) * 4225;  // contiguous (c,d) plane
  for (int idx = threadIdx.x; idx < 4225; idx += 256) {
    int c = idx / 65, d = idx - c * 65;
    tile[d * 66 + c] = __float2bfloat16(src[idx]);
  }
  __syncthreads();
  for (int idx = threadIdx.x; idx < 4225; idx += 256) {
    int d = idx / 65, c = idx - d * 65;
    Wt2[(size_t)(b * 65 + d) * KP + a * 65 + c] = tile[d * 66 + c];
  }
}

// ---------------- P/R builder: P[row][x*65+y] = layer_row[x] * h_row[y] ----------------
__global__ void build_p(const float* __restrict__ layer, const float* __restrict__ h,
                        __hip_bfloat16* __restrict__ P, int width) {
  const int row = blockIdx.x;
  __shared__ float lv[65], hv[65];
  if (threadIdx.x < 64) lv[threadIdx.x] = layer[(size_t)row * 64 + threadIdx.x];
  if (threadIdx.x == 64) lv[64] = 1.0f;
  if (threadIdx.x < 65) hv[threadIdx.x] = h[(size_t)row * 65 + threadIdx.x];
  __syncthreads();
  for (int base = threadIdx.x * 8; base < width; base += 256 * 8) {
    alignas(16) __hip_bfloat16 tmp[8];
#pragma unroll
    for (int j = 0; j < 8; ++j) {
      int idx = base + j;
      float v = 0.f;
      if (idx < 4225) {
        int x = idx / 65, y = idx - x * 65;
        v = lv[x] * hv[y];
      }
      tmp[j] = __float2bfloat16(v);
    }
    *(float4*)(P + (size_t)row * width + base) = *(const float4*)tmp;
  }
}

// ---------------- gemm1: deep-pipelined 256x256 NT GEMM, bf16 out ----------------
// C[i][j] = sum_k A[i][k]*B[j][k]. Requires M%256==0, N%256==0, K%32==0, K/32>=3.
//
// LDS ring: 4 buffers x (A 256x32 + B 256x32) bf16 = 128 KiB. Iteration kt
// computes buf kt&3 and issues tile kt+2 into buf (kt+2)&3 (that buf was
// last READ in iteration kt-2, two barriers ago -> WAR-safe). Boundary:
//   s_waitcnt vmcnt(4)  -- 4 newest loads (tile kt+2) stay in flight,
//                          tile kt+1 (issued last iter) forced complete
//   s_barrier           -- same asm block, so LDS reads can't cross it
// Exactly 4 global_load_lds per thread per iteration keeps the count exact.
//
// Swizzle: LDS row = 64B = 4 x 16B chunks; physical chunk p of row holds
// global chunk c = p ^ (row&3). DMA dest stays linear (wave base + lane*16),
// the permutation is applied on the GLOBAL source (rule: both-sides via
// pre-swizzled src). ds_read reads chunk (ks*2+lhi)^(l31&3): each bank gets
// exactly 8 accesses/wave (minimum) for reads; DMA writes are contiguous 1KB.
__global__ __launch_bounds__(512) void gemm1_256(
    const __hip_bfloat16* __restrict__ A, const __hip_bfloat16* __restrict__ B,
    __hip_bfloat16* __restrict__ C, int K, int lda, int ldb, int ldc) {
  __shared__ alignas(16) __hip_bfloat16 As[4 * 256 * 32];
  __shared__ alignas(16) __hip_bfloat16 Bs[4 * 256 * 32];
  const int bn = blockIdx.x * 256;
  const int bm = blockIdx.y * 256;
  const int t = threadIdx.x;
  const int lane = t & 63;
  const int w = t >> 6;          // wave 0..7, grid 2(M) x 4(N)
  const int l31 = lane & 31;
  const int lhi = lane >> 5;     // k-half of the 32x32 fragment
  const int x3 = l31 & 3;        // row&3 for all fragment rows
  const int wm = (w >> 2) * 128; // wave M offset: 0/128
  const int wn = (w & 3) * 64;   // wave N offset: 0..192

  // staging: per buffer 1024 chunks of 16B for A (and B); thread handles
  // chunks L = r*512 + t (r=0,1). LDS linear; global src carries the swizzle.
  const __hip_bfloat16* gA[2];
  const __hip_bfloat16* gB[2];
  int ldsOff[2];  // wave-uniform element offset (DMA adds lane*16 bytes)
#pragma unroll
  for (int r = 0; r < 2; ++r) {
    int L = r * 512 + t;
    int row = L >> 2, p = L & 3;
    int c = p ^ (row & 3);
    gA[r] = A + (size_t)(bm + row) * lda + c * 8;
    gB[r] = B + (size_t)(bn + row) * ldb + c * 8;
    ldsOff[r] = r * 4096 + w * 512;
  }

  // fragment row bases (elements): row = wm + mf*32 + l31, stride 32 bf16
  int rA[4], rB[2];
#pragma unroll
  for (int mf = 0; mf < 4; ++mf) rA[mf] = (wm + mf * 32 + l31) * 32;
#pragma unroll
  for (int nf = 0; nf < 2; ++nf) rB[nf] = (wn + nf * 32 + l31) * 32;

  const int NT = K >> 5;  // # of 32-wide K-tiles (>= 3 for our shapes)

  // prologue: stage tiles 0,1 into bufs 0,1 (8 loads), need tile 0 -> vmcnt(4)
#pragma unroll
  for (int tt = 0; tt < 2; ++tt) {
#pragma unroll
    for (int r = 0; r < 2; ++r) {
      async_ld16(gA[r] + tt * 32, As + tt * 8192 + ldsOff[r]);
      async_ld16(gB[r] + tt * 32, Bs + tt * 8192 + ldsOff[r]);
    }
  }
  asm volatile("s_waitcnt vmcnt(4)\n\ts_barrier" ::: "memory");

  floatx16 acc[4][2] = {};  // per-wave 128x64 = 4x2 tiles of 32x32

  for (int kt = 0; kt < NT; ++kt) {
    // issue tile kt+2 into buf (kt+2)&3 (freed two barriers ago)
    if (kt + 2 < NT) {
      const int k0 = (kt + 2) * 32;
      const int bo = ((kt + 2) & 3) * 8192;
#pragma unroll
      for (int r = 0; r < 2; ++r) {
        async_ld16(gA[r] + k0, As + bo + ldsOff[r]);
        async_ld16(gB[r] + k0, Bs + bo + ldsOff[r]);
      }
      __builtin_amdgcn_sched_barrier(0);  // pin issue before compute
    }
    const __hip_bfloat16* Ab = As + (kt & 3) * 8192;
    const __hip_bfloat16* Bb = Bs + (kt & 3) * 8192;
    short8 a[4][2], b[2][2];
#pragma unroll
    for (int ks = 0; ks < 2; ++ks) {
      const int pc = ((ks * 2 + lhi) ^ x3) * 8;  // swizzled chunk -> elem off
#pragma unroll
      for (int mf = 0; mf < 4; ++mf) a[mf][ks] = *(const short8*)(Ab + rA[mf] + pc);
#pragma unroll
      for (int nf = 0; nf < 2; ++nf) b[nf][ks] = *(const short8*)(Bb + rB[nf] + pc);
    }
    __builtin_amdgcn_s_setprio(1);
#pragma unroll
    for (int ks = 0; ks < 2; ++ks)
#pragma unroll
      for (int mf = 0; mf < 4; ++mf)
#pragma unroll
        for (int nf = 0; nf < 2; ++nf)
          acc[mf][nf] = __builtin_amdgcn_mfma_f32_32x32x16_bf16(
              a[mf][ks], b[nf][ks], acc[mf][nf], 0, 0, 0);
    __builtin_amdgcn_s_setprio(0);
    if (kt + 1 < NT) {
      if (kt + 2 < NT)  // counted: tile kt+2's 4 loads stay in flight
        asm volatile("s_waitcnt vmcnt(4) lgkmcnt(0)\n\ts_barrier" ::: "memory");
      else              // last prefetched tile: full drain (once)
        asm volatile("s_waitcnt vmcnt(0) lgkmcnt(0)\n\ts_barrier" ::: "memory");
    }
  }

  // C/D layout (verified m74/m101): col = lane&31,
  // row = (reg&3) + 8*(reg>>2) + 4*(lane>>5)
#pragma unroll
  for (int mf = 0; mf < 4; ++mf)
#pragma unroll
    for (int nf = 0; nf < 2; ++nf)
#pragma unroll
      for (int reg = 0; reg < 16; ++reg) {
        int row = bm + wm + mf * 32 + (reg & 3) + 8 * (reg >> 2) + 4 * lhi;
        int col = bn + wn + nf * 32 + l31;
        C[(size_t)row * ldc + col] = __float2bfloat16(acc[mf][nf][reg]);
      }
}

// ---------------- NT GEMM (R3 kernel, kept for gemm2) ----------------
// A: M x K (lda), B: N x K (ldb), row-major bf16, K % 64 == 0.
// 128x128 block tile, 4 waves each 64x64 = 2x2 tiles of 32x32, BK=64,
// mfma_f32_32x32x16_bf16. Staging via global_load_lds x16, XOR-swizzled LDS.
template <int STORE_BF16>
__global__ __launch_bounds__(256) void gemm_nt(
    const __hip_bfloat16* __restrict__ A, const __hip_bfloat16* __restrict__ B,
    void* __restrict__ Cv, int K, int lda, int ldb, int ldc,
    long sA, long sB, long sC) {
  __shared__ alignas(16) __hip_bfloat16 As[128 * 64];
  __shared__ alignas(16) __hip_bfloat16 Bs[128 * 64];
  const int z = blockIdx.z;
  A += (long)z * sA;
  B += (long)z * sB;
  const int bm = blockIdx.y * 128;
  const int bn = blockIdx.x * 128;
  const int t = threadIdx.x;
  const int lane = t & 63;
  const int wave = t >> 6;
  const int l31 = lane & 31;
  const int lhi = lane >> 5;
  const int wm = (wave >> 1) * 64;
  const int wn = (wave & 1) * 64;

  const __hip_bfloat16* gA[4];
  const __hip_bfloat16* gB[4];
  __hip_bfloat16* lA[4];
  __hip_bfloat16* lB[4];
#pragma unroll
  for (int r = 0; r < 4; ++r) {
    int L = r * 256 + t;
    int row = L >> 3, sl = L & 7;
    int sg = sl ^ (row & 7);
    gA[r] = A + (size_t)(bm + row) * lda + sg * 8;
    gB[r] = B + (size_t)(bn + row) * ldb + sg * 8;
    lA[r] = As + (size_t)(r * 256 + wave * 64) * 8;
    lB[r] = Bs + (size_t)(r * 256 + wave * 64) * 8;
  }

  const int x7 = l31 & 7;
  const int rA0 = (wm + l31) * 64, rA1 = (wm + 32 + l31) * 64;
  const int rB0 = (wn + l31) * 64, rB1 = (wn + 32 + l31) * 64;

  floatx16 acc[2][2] = {};

  for (int k0 = 0; k0 < K; k0 += 64) {
    __syncthreads();
#pragma unroll
    for (int r = 0; r < 4; ++r) {
      async_ld16(gA[r] + k0, lA[r]);
      async_ld16(gB[r] + k0, lB[r]);
    }
    __syncthreads();

#pragma unroll
    for (int ks = 0; ks < 4; ++ks) {
      const int pc = ((ks * 2 + lhi) ^ x7) * 8;
      short8 a0 = *(const short8*)(&As[rA0 + pc]);
      short8 a1 = *(const short8*)(&As[rA1 + pc]);
      short8 b0 = *(const short8*)(&Bs[rB0 + pc]);
      short8 b1 = *(const short8*)(&Bs[rB1 + pc]);
      acc[0][0] = __builtin_amdgcn_mfma_f32_32x32x16_bf16(a0, b0, acc[0][0], 0, 0, 0);
      acc[0][1] = __builtin_amdgcn_mfma_f32_32x32x16_bf16(a0, b1, acc[0][1], 0, 0, 0);
      acc[1][0] = __builtin_amdgcn_mfma_f32_32x32x16_bf16(a1, b0, acc[1][0], 0, 0, 0);
      acc[1][1] = __builtin_amdgcn_mfma_f32_32x32x16_bf16(a1, b1, acc[1][1], 0, 0, 0);
    }
  }

  if (STORE_BF16) {
    __hip_bfloat16* C = (__hip_bfloat16*)Cv + (long)z * sC;
#pragma unroll
    for (int mt = 0; mt < 2; ++mt)
#pragma unroll
      for (int nt = 0; nt < 2; ++nt)
#pragma unroll
        for (int reg = 0; reg < 16; ++reg) {
          int row = bm + wm + mt * 32 + (reg & 3) + 8 * (reg >> 2) + 4 * lhi;
          int col = bn + wn + nt * 32 + l31;
          C[(size_t)row * ldc + col] = __float2bfloat16(acc[mt][nt][reg]);
        }
  } else {
    float* C = (float*)Cv + (long)z * sC;
#pragma unroll
    for (int mt = 0; mt < 2; ++mt)
#pragma unroll
      for (int nt = 0; nt < 2; ++nt)
#pragma unroll
        for (int reg = 0; reg < 16; ++reg) {
          int row = bm + wm + mt * 32 + (reg & 3) + 8 * (reg >> 2) + 4 * lhi;
          int col = bn + wn + nt * 32 + l31;
          C[(size_t)row * ldc + col] = acc[mt][nt][reg];
        }
  }
}

extern "C" void kernel_launch(void* const* d_in, const int* in_sizes, int n_in,
                              void* d_out, int out_size, void* d_ws, size_t ws_size,
                              hipStream_t stream) {
  const float* layer1 = (const float*)d_in[0];
  const float* layer2 = (const float*)d_in[1];
  const float* h1 = (const float*)d_in[3];
  const float* h2 = (const float*)d_in[4];
  const float* W = (const float*)d_in[6];
  float* out = (float*)d_out;

  // workspace layout (bytes), total high-water 178,880,512:
  //   [0 .. 70,254,592)            P  (8192*4288*2)   -- later reused for R
  //   [70,254,592 .. 107,577,344)  Wt2 (4352*4288*2)
  //   [107,577,344 .. 178,880,512) Q  (8192*4352*2)
  char* ws = (char*)d_ws;
  __hip_bfloat16* P = (__hip_bfloat16*)(ws);
  __hip_bfloat16* Wt2 = (__hip_bfloat16*)(ws + 70254592ULL);
  __hip_bfloat16* Q = (__hip_bfloat16*)(ws + 107577344ULL);
  __hip_bfloat16* R = (__hip_bfloat16*)(ws);  // reuses P/Wt2 region

  // 1) zero Wt2 (covers pad rows/cols; real entries overwritten next)
  zero_kernel<<<2048, 256, 0, stream>>>((float4*)Wt2, (long)DP * KP * 2 / 16);
  // 2) transpose+cast W
  build_wt2<<<dim3(65, 65), 256, 0, stream>>>(W, Wt2);
  // 3) P
  build_p<<<NROW, 256, 0, stream>>>(layer1, h1, P, KP);
  // 4) Q = P @ Wt2 (NT): M=8192, N=4352, K=4288 — deep-pipelined 256^2 kernel
  gemm1_256<<<dim3(DP / 256, NROW / 256), 512, 0, stream>>>(
      P, Wt2, Q, KP, KP, KP, DP);
  // 5) R (over the now-dead P/Wt2 region)
  build_p<<<NROW, 256, 0, stream>>>(layer2, h2, R, DP);
  // 6) out_n = Q_n @ R_n^T: M=N=1024, K=4352, batched over n=8
  gemm_nt<0><<<dim3(1024 / 128, 1024 / 128, 8), 256, 0, stream>>>(
      Q, R, out, DP, DP, DP, 1024, 1024L * DP, 1024L * DP, 1024L * 1024);
}

// Round 3
// 700.855 us; speedup vs baseline: 1.2071x; 1.2071x over previous
//
#include <hip/hip_runtime.h>
#include <hip/hip_bf16.h>

// Qriaffine: out[n,i,j] = sum_{a,b,c,d} l1[n,i,a] W[a,b,c,d] l2[n,j,b] h1[n,i,c] h2[n,j,d]
// Plan:
//   P[(n,i)][(a*65+c)] = l1[a]*h1[c]        (8192 x 4225, bf16, pad K->4288)
//   Wt2[(b*65+d)][(a*65+c)] = W[a,b,c,d]    (4225 x 4225, bf16, pad -> 4352 x 4288)
//   Q = P @ Wt2 (NT gemm)                   (8192 x 4352, bf16)
//   R[(n,j)][(b*65+d)] = l2[b]*h2[d]        (8192 x 4352, bf16, built AFTER gemm1)
//   out_n = Q_n @ R_n^T (NT gemm, f32 out)  (8 x 1024 x 1024)
//
// R5: post-mortem of R4 (620us, conflicts 2.3x UP, 1 block/CU): (a) the
// row&3 chunk-XOR is wrong for 64B rows -- row parity adds bank-bit 4, so
// 16-lane groups hit half the banks 4-way. Fix: chunk ^= (row>>1)&3 (each
// 16-lane group then covers all 8 bank-quads exactly 2x = minimum).
// (b) 128KiB LDS -> 1 block/CU removed the multi-block TLP that made R3
// fast; hand-rolled distance-2 vmcnt pipelines don't survive the compiler
// (m131-m141). R3 itself is LDS-BW-bound (39% MfmaUtil x 512B/MFMA-pair
// ~= 78% of 256B/cy LDS peak).
// => gemm1 now: 128x128 tile, 2 waves/block each 128x64 (0.75KB LDS per
// MFMA, -25% vs R3), BK=32, 2-deep ring = 32KiB LDS -> 5 blocks/CU (TLP
// regime restored), distance-1 prefetch (reads first, then issue, drain at
// iter end -- compiler alias conservatism is then free), fixed swizzle.
// gemm2 keeps the R3 128x128 kernel unchanged.

typedef __attribute__((ext_vector_type(8))) short short8;     // 8 bf16 = 4 VGPRs
typedef __attribute__((ext_vector_type(16))) float floatx16;  // MFMA 32x32 acc

#define KP 4288   // padded (a,c) dim: 67*64
#define DP 4352   // padded (b,d) dim: 68*64 = 34*128
#define NROW 8192 // n*L

__device__ __forceinline__ void async_ld16(const void* g, void* l) {
  __builtin_amdgcn_global_load_lds(
      (const __attribute__((address_space(1))) unsigned int*)g,
      (__attribute__((address_space(3))) unsigned int*)l, 16, 0, 0);
}

// ---------------- zero helper (16B granularity) ----------------
__global__ void zero_kernel(float4* __restrict__ p, long n) {
  long i = (long)blockIdx.x * blockDim.x + threadIdx.x;
  long stride = (long)gridDim.x * blockDim.x;
  float4 z = make_float4(0.f, 0.f, 0.f, 0.f);
  for (; i < n; i += stride) p[i] = z;
}

// ---------------- W[a,b,c,d] -> Wt2[(b*65+d)][(a*65+c)] (bf16) ----------------
__global__ void build_wt2(const float* __restrict__ W, __hip_bfloat16* __restrict__ Wt2) {
  __shared__ __hip_bfloat16 tile[65 * 66];
  const int a = blockIdx.x, b = blockIdx.y;
  const float* src = W + (size_t)(a * 65 + b) * 4225;  // contiguous (c,d) plane
  for (int idx = threadIdx.x; idx < 4225; idx += 256) {
    int c = idx / 65, d = idx - c * 65;
    tile[d * 66 + c] = __float2bfloat16(src[idx]);
  }
  __syncthreads();
  for (int idx = threadIdx.x; idx < 4225; idx += 256) {
    int d = idx / 65, c = idx - d * 65;
    Wt2[(size_t)(b * 65 + d) * KP + a * 65 + c] = tile[d * 66 + c];
  }
}

// ---------------- P/R builder: P[row][x*65+y] = layer_row[x] * h_row[y] ----------------
__global__ void build_p(const float* __restrict__ layer, const float* __restrict__ h,
                        __hip_bfloat16* __restrict__ P, int width) {
  const int row = blockIdx.x;
  __shared__ float lv[65], hv[65];
  if (threadIdx.x < 64) lv[threadIdx.x] = layer[(size_t)row * 64 + threadIdx.x];
  if (threadIdx.x == 64) lv[64] = 1.0f;
  if (threadIdx.x < 65) hv[threadIdx.x] = h[(size_t)row * 65 + threadIdx.x];
  __syncthreads();
  for (int base = threadIdx.x * 8; base < width; base += 256 * 8) {
    alignas(16) __hip_bfloat16 tmp[8];
#pragma unroll
    for (int j = 0; j < 8; ++j) {
      int idx = base + j;
      float v = 0.f;
      if (idx < 4225) {
        int x = idx / 65, y = idx - x * 65;
        v = lv[x] * hv[y];
      }
      tmp[j] = __float2bfloat16(v);
    }
    *(float4*)(P + (size_t)row * width + base) = *(const float4*)tmp;
  }
}

// ---------------- gemm1: 128x128 NT GEMM, 2 waves x (128x64), bf16 out ----------------
// C[i][j] = sum_k A[i][k]*B[j][k]. M%128==0, N%128==0, K%32==0, K/32>=2.
//
// 2-deep LDS ring: 2 x (A 128x32 + B 128x32) bf16 = 32 KiB -> 5 blocks/CU.
// Iteration kt: ds_read frags from buf kt&1 (DMA-drained at end of kt-1),
// then issue tile kt+1 into buf (kt+1)&1 (its readers, iter kt-1, finished
// before the last barrier's lgkmcnt(0)), then 16 MFMA, then
//   s_waitcnt vmcnt(0) lgkmcnt(0); s_barrier   (one asm block)
// Reads-before-issue ordering means any compiler-inserted conservative
// vmcnt before the LDS reads is a no-op (already drained at iter start).
// Load latency is hidden by the 5-way block TLP (m114 mechanism), not by
// in-block pipelining.
//
// Swizzle (64B rows = 4 x 16B chunks): physical chunk p of row r holds
// global chunk c = p ^ ((r>>1)&3). For a wave's ds_read_b128 (row stride
// 64B: bank base = 16*(row&1) + 4*chunk mod 32), each 16-lane group covers
// all 8 bank-quads exactly twice = conflict-minimum. DMA dest stays linear
// (wave base + lane*16); the permutation rides on the GLOBAL source, and
// the 4 lanes of a row still cover one whole 64B line (coalesced).
__global__ __launch_bounds__(128) void gemm_nt_w2(
    const __hip_bfloat16* __restrict__ A, const __hip_bfloat16* __restrict__ B,
    __hip_bfloat16* __restrict__ C, int K, int lda, int ldb, int ldc) {
  __shared__ alignas(16) __hip_bfloat16 As[2 * 128 * 32];
  __shared__ alignas(16) __hip_bfloat16 Bs[2 * 128 * 32];
  const int bn = blockIdx.x * 128;
  const int bm = blockIdx.y * 128;
  const int t = threadIdx.x;   // 0..127
  const int lane = t & 63;
  const int w = t >> 6;        // wave 0..1 -> N-halves
  const int l31 = lane & 31;
  const int lhi = lane >> 5;   // k-half of the 32x32 fragment
  const int x3 = (l31 >> 1) & 3;
  const int wn = w * 64;

  // staging: 512 chunks of 16B per 128x32 tile; thread t handles chunks
  // L = r*128 + t (r=0..3). LDS linear; global src carries the swizzle.
  const __hip_bfloat16* gA[4];
  const __hip_bfloat16* gB[4];
  int ldsOff[4];  // wave-uniform element offset (DMA adds lane*16 bytes)
#pragma unroll
  for (int r = 0; r < 4; ++r) {
    int L = r * 128 + t;
    int row = L >> 2, p = L & 3;
    int c = p ^ ((row >> 1) & 3);
    gA[r] = A + (size_t)(bm + row) * lda + c * 8;
    gB[r] = B + (size_t)(bn + row) * ldb + c * 8;
    ldsOff[r] = r * 1024 + w * 512;
  }

  // fragment row bases (elements): row = mf*32 + l31 (A), wn + nf*32 + l31 (B)
  int rA[4], rB[2];
#pragma unroll
  for (int mf = 0; mf < 4; ++mf) rA[mf] = (mf * 32 + l31) * 32;
#pragma unroll
  for (int nf = 0; nf < 2; ++nf) rB[nf] = (wn + nf * 32 + l31) * 32;

  const int NT = K >> 5;

  // prologue: stage tile 0 into buf 0
#pragma unroll
  for (int r = 0; r < 4; ++r) {
    async_ld16(gA[r], As + ldsOff[r]);
    async_ld16(gB[r], Bs + ldsOff[r]);
  }
  asm volatile("s_waitcnt vmcnt(0)\n\ts_barrier" ::: "memory");

  floatx16 acc[4][2] = {};  // per-wave 128x64 = 4x2 tiles of 32x32

  for (int kt = 0; kt < NT; ++kt) {
    const __hip_bfloat16* Ab = As + (kt & 1) * 4096;
    const __hip_bfloat16* Bb = Bs + (kt & 1) * 4096;
    short8 a[4][2], b[2][2];
#pragma unroll
    for (int ks = 0; ks < 2; ++ks) {
      const int pc = ((ks * 2 + lhi) ^ x3) * 8;  // swizzled chunk -> elem off
#pragma unroll
      for (int mf = 0; mf < 4; ++mf) a[mf][ks] = *(const short8*)(Ab + rA[mf] + pc);
#pragma unroll
      for (int nf = 0; nf < 2; ++nf) b[nf][ks] = *(const short8*)(Bb + rB[nf] + pc);
    }
    // issue next tile into the other buffer (its readers drained at the
    // last barrier's lgkmcnt(0); different buffer than this iter's reads)
    if (kt + 1 < NT) {
      const int k0 = (kt + 1) * 32;
      const int bo = ((kt + 1) & 1) * 4096;
#pragma unroll
      for (int r = 0; r < 4; ++r) {
        async_ld16(gA[r] + k0, As + bo + ldsOff[r]);
        async_ld16(gB[r] + k0, Bs + bo + ldsOff[r]);
      }
    }
    __builtin_amdgcn_sched_barrier(0);  // keep issues ahead of the MFMA block
#pragma unroll
    for (int ks = 0; ks < 2; ++ks)
#pragma unroll
      for (int mf = 0; mf < 4; ++mf)
#pragma unroll
        for (int nf = 0; nf < 2; ++nf)
          acc[mf][nf] = __builtin_amdgcn_mfma_f32_32x32x16_bf16(
              a[mf][ks], b[nf][ks], acc[mf][nf], 0, 0, 0);
    if (kt + 1 < NT)
      asm volatile("s_waitcnt vmcnt(0) lgkmcnt(0)\n\ts_barrier" ::: "memory");
  }

  // C/D layout (verified m74/m101): col = lane&31,
  // row = (reg&3) + 8*(reg>>2) + 4*(lane>>5)
#pragma unroll
  for (int mf = 0; mf < 4; ++mf)
#pragma unroll
    for (int nf = 0; nf < 2; ++nf)
#pragma unroll
      for (int reg = 0; reg < 16; ++reg) {
        int row = bm + mf * 32 + (reg & 3) + 8 * (reg >> 2) + 4 * lhi;
        int col = bn + wn + nf * 32 + l31;
        C[(size_t)row * ldc + col] = __float2bfloat16(acc[mf][nf][reg]);
      }
}

// ---------------- NT GEMM (R3 kernel, kept for gemm2) ----------------
// A: M x K (lda), B: N x K (ldb), row-major bf16, K % 64 == 0.
// 128x128 block tile, 4 waves each 64x64 = 2x2 tiles of 32x32, BK=64,
// mfma_f32_32x32x16_bf16. Staging via global_load_lds x16, XOR-swizzled LDS.
template <int STORE_BF16>
__global__ __launch_bounds__(256) void gemm_nt(
    const __hip_bfloat16* __restrict__ A, const __hip_bfloat16* __restrict__ B,
    void* __restrict__ Cv, int K, int lda, int ldb, int ldc,
    long sA, long sB, long sC) {
  __shared__ alignas(16) __hip_bfloat16 As[128 * 64];
  __shared__ alignas(16) __hip_bfloat16 Bs[128 * 64];
  const int z = blockIdx.z;
  A += (long)z * sA;
  B += (long)z * sB;
  const int bm = blockIdx.y * 128;
  const int bn = blockIdx.x * 128;
  const int t = threadIdx.x;
  const int lane = t & 63;
  const int wave = t >> 6;
  const int l31 = lane & 31;
  const int lhi = lane >> 5;
  const int wm = (wave >> 1) * 64;
  const int wn = (wave & 1) * 64;

  const __hip_bfloat16* gA[4];
  const __hip_bfloat16* gB[4];
  __hip_bfloat16* lA[4];
  __hip_bfloat16* lB[4];
#pragma unroll
  for (int r = 0; r < 4; ++r) {
    int L = r * 256 + t;
    int row = L >> 3, sl = L & 7;
    int sg = sl ^ (row & 7);
    gA[r] = A + (size_t)(bm + row) * lda + sg * 8;
    gB[r] = B + (size_t)(bn + row) * ldb + sg * 8;
    lA[r] = As + (size_t)(r * 256 + wave * 64) * 8;
    lB[r] = Bs + (size_t)(r * 256 + wave * 64) * 8;
  }

  const int x7 = l31 & 7;
  const int rA0 = (wm + l31) * 64, rA1 = (wm + 32 + l31) * 64;
  const int rB0 = (wn + l31) * 64, rB1 = (wn + 32 + l31) * 64;

  floatx16 acc[2][2] = {};

  for (int k0 = 0; k0 < K; k0 += 64) {
    __syncthreads();
#pragma unroll
    for (int r = 0; r < 4; ++r) {
      async_ld16(gA[r] + k0, lA[r]);
      async_ld16(gB[r] + k0, lB[r]);
    }
    __syncthreads();

#pragma unroll
    for (int ks = 0; ks < 4; ++ks) {
      const int pc = ((ks * 2 + lhi) ^ x7) * 8;
      short8 a0 = *(const short8*)(&As[rA0 + pc]);
      short8 a1 = *(const short8*)(&As[rA1 + pc]);
      short8 b0 = *(const short8*)(&Bs[rB0 + pc]);
      short8 b1 = *(const short8*)(&Bs[rB1 + pc]);
      acc[0][0] = __builtin_amdgcn_mfma_f32_32x32x16_bf16(a0, b0, acc[0][0], 0, 0, 0);
      acc[0][1] = __builtin_amdgcn_mfma_f32_32x32x16_bf16(a0, b1, acc[0][1], 0, 0, 0);
      acc[1][0] = __builtin_amdgcn_mfma_f32_32x32x16_bf16(a1, b0, acc[1][0], 0, 0, 0);
      acc[1][1] = __builtin_amdgcn_mfma_f32_32x32x16_bf16(a1, b1, acc[1][1], 0, 0, 0);
    }
  }

  if (STORE_BF16) {
    __hip_bfloat16* C = (__hip_bfloat16*)Cv + (long)z * sC;
#pragma unroll
    for (int mt = 0; mt < 2; ++mt)
#pragma unroll
      for (int nt = 0; nt < 2; ++nt)
#pragma unroll
        for (int reg = 0; reg < 16; ++reg) {
          int row = bm + wm + mt * 32 + (reg & 3) + 8 * (reg >> 2) + 4 * lhi;
          int col = bn + wn + nt * 32 + l31;
          C[(size_t)row * ldc + col] = __float2bfloat16(acc[mt][nt][reg]);
        }
  } else {
    float* C = (float*)Cv + (long)z * sC;
#pragma unroll
    for (int mt = 0; mt < 2; ++mt)
#pragma unroll
      for (int nt = 0; nt < 2; ++nt)
#pragma unroll
        for (int reg = 0; reg < 16; ++reg) {
          int row = bm + wm + mt * 32 + (reg & 3) + 8 * (reg >> 2) + 4 * lhi;
          int col = bn + wn + nt * 32 + l31;
          C[(size_t)row * ldc + col] = acc[mt][nt][reg];
        }
  }
}

extern "C" void kernel_launch(void* const* d_in, const int* in_sizes, int n_in,
                              void* d_out, int out_size, void* d_ws, size_t ws_size,
                              hipStream_t stream) {
  const float* layer1 = (const float*)d_in[0];
  const float* layer2 = (const float*)d_in[1];
  const float* h1 = (const float*)d_in[3];
  const float* h2 = (const float*)d_in[4];
  const float* W = (const float*)d_in[6];
  float* out = (float*)d_out;

  // workspace layout (bytes), total high-water 178,880,512:
  //   [0 .. 70,254,592)            P  (8192*4288*2)   -- later reused for R
  //   [70,254,592 .. 107,577,344)  Wt2 (4352*4288*2)
  //   [107,577,344 .. 178,880,512) Q  (8192*4352*2)
  char* ws = (char*)d_ws;
  __hip_bfloat16* P = (__hip_bfloat16*)(ws);
  __hip_bfloat16* Wt2 = (__hip_bfloat16*)(ws + 70254592ULL);
  __hip_bfloat16* Q = (__hip_bfloat16*)(ws + 107577344ULL);
  __hip_bfloat16* R = (__hip_bfloat16*)(ws);  // reuses P/Wt2 region

  // 1) zero Wt2 (covers pad rows/cols; real entries overwritten next)
  zero_kernel<<<2048, 256, 0, stream>>>((float4*)Wt2, (long)DP * KP * 2 / 16);
  // 2) transpose+cast W
  build_wt2<<<dim3(65, 65), 256, 0, stream>>>(W, Wt2);
  // 3) P
  build_p<<<NROW, 256, 0, stream>>>(layer1, h1, P, KP);
  // 4) Q = P @ Wt2 (NT): M=8192, N=4352, K=4288 — 2-wave 128x128 kernel
  gemm_nt_w2<<<dim3(DP / 128, NROW / 128), 128, 0, stream>>>(
      P, Wt2, Q, KP, KP, KP, DP);
  // 5) R (over the now-dead P/Wt2 region)
  build_p<<<NROW, 256, 0, stream>>>(layer2, h2, R, DP);
  // 6) out_n = Q_n @ R_n^T: M=N=1024, K=4352, batched over n=8
  gemm_nt<0><<<dim3(1024 / 128, 1024 / 128, 8), 256, 0, stream>>>(
      Q, R, out, DP, DP, DP, 1024, 1024L * DP, 1024L * DP, 1024L * 1024);
}